// Round 3
// baseline (365.225 us; speedup 1.0000x reference)
//
#include <hip/hip_runtime.h>
#include <hip/hip_cooperative_groups.h>

namespace cg = cooperative_groups;

// Problem constants (B,T,H,D,M) = (2, 2048, 8, 64, 64), fp32 in/out.
#define BB 2
#define TT 2048
#define HH 8
#define DD 64
#define CC 256           // chunks over T
#define TC (TT / CC)     // 8 timesteps per chunk (= 4 segs x 2 iters)
#define STRIDE (HH * DD) // 512 floats between consecutive timesteps
#define NWAVE (BB * HH * CC)        // 4096 waves, one per chunk
#define GS_OFF ((size_t)NWAVE * DD) // float offset of group sums inside out

__device__ __forceinline__ float feat(float x) {
    // elu(x) + 1 = x+1 (x>0) else exp(x)
    return x > 0.f ? x + 1.f : __expf(x);
}

__device__ __forceinline__ void feat4(float4& a) {
    a.x = feat(a.x); a.y = feat(a.y); a.z = feat(a.z); a.w = feat(a.w);
}

// Sum the 4 seg groups' values into every lane (butterfly over lanes ^16, ^32).
__device__ __forceinline__ void xorred4(float4& a) {
    a.x += __shfl_xor(a.x, 16, 64); a.y += __shfl_xor(a.y, 16, 64);
    a.z += __shfl_xor(a.z, 16, 64); a.w += __shfl_xor(a.w, 16, 64);
    a.x += __shfl_xor(a.x, 32, 64); a.y += __shfl_xor(a.y, 32, 64);
    a.z += __shfl_xor(a.z, 32, 64); a.w += __shfl_xor(a.w, 32, 64);
}

// Lane map: g = lane&15 -> d-group (d = 4g..4g+3), seg = lane>>4 -> timestep
// within group-of-4. One wave float4-load = 4 timesteps x 64 d = 1 KB.
//
// Single cooperative kernel, 4 phases separated by grid syncs:
//  1) load k/q/v (kept in registers), chunk sums of feat(k) -> scratch
//  2) 16-chunk group sums (256 waves)                       -> scratch
//  3) hierarchical carry lookback (<=4+4 float4/lane, L2), full compute
//  4) write out (after a sync so scratch reads are all done)
// Scratch lives in the low 1.0625 MB of `out` — d_ws is NOT used.
__global__ void __launch_bounds__(256, 4)
fused_kernel(const float* __restrict__ q, const float* __restrict__ k,
             const float* __restrict__ v, float* __restrict__ out) {
    const int W    = blockIdx.x * 4 + (threadIdx.x >> 6); // wave id = chunk id
    const int lane = threadIdx.x & 63;
    const int c    = W & (CC - 1);
    const int h    = (W >> 8) & (HH - 1);
    const int b    = W >> 11;
    const int g    = lane & 15;
    const int seg  = lane >> 4;

    float* chunkS = out;          // [NWAVE][DD]  chunk sums
    float* groupS = out + GS_OFF; // [16][16][DD] 16-chunk group sums

    // lane's timesteps: t0 = c*TC + seg (iter 0), t0+4 (iter 1); d = 4g..4g+3
    const size_t off0 = (((size_t)b * TT + c * TC + seg) * HH + h) * DD + g * 4;
    const size_t off1 = off0 + (size_t)4 * STRIDE;

    float4 kf0 = *(const float4*)(k + off0);
    float4 kf1 = *(const float4*)(k + off1);
    float4 qf0 = *(const float4*)(q + off0);
    float4 qf1 = *(const float4*)(q + off1);
    const float4 vv0 = *(const float4*)(v + off0);
    const float4 vv1 = *(const float4*)(v + off1);

    feat4(kf0); feat4(kf1); feat4(qf0); feat4(qf1);

    // ---- phase 1: chunk sum over the 8 timesteps
    float4 s;
    s.x = kf0.x + kf1.x; s.y = kf0.y + kf1.y;
    s.z = kf0.z + kf1.z; s.w = kf0.w + kf1.w;
    xorred4(s);
    if (seg == 0)
        *(float4*)(chunkS + (size_t)W * DD + g * 4) = s;

    cg::this_grid().sync();

    // ---- phase 2: group sums (16 chunks each) by the first 256 waves
    if (W < 256) {
        const int bh2 = W >> 4, g16 = W & 15;
        const float* cs = chunkS + ((size_t)bh2 * CC + g16 * 16) * DD + g * 4;
        float4 t = make_float4(0.f, 0.f, 0.f, 0.f);
        #pragma unroll
        for (int i = 0; i < 4; ++i) {
            const float4 a = *(const float4*)(cs + (size_t)(seg + 4 * i) * DD);
            t.x += a.x; t.y += a.y; t.z += a.z; t.w += a.w;
        }
        xorred4(t);
        if (seg == 0)
            *(float4*)(groupS + (size_t)W * DD + g * 4) = t;
    }

    cg::this_grid().sync();

    // ---- phase 3a: exclusive chunk carry = full groups + chunks within group
    const int bh = W >> 8;
    float4 carry = make_float4(0.f, 0.f, 0.f, 0.f);
    const int ng = c >> 4;   // full groups before this chunk's group
    const float* gsb = groupS + ((size_t)bh * 16) * DD + g * 4;
    for (int gp = seg; gp < ng; gp += 4) {
        const float4 t = *(const float4*)(gsb + (size_t)gp * DD);
        carry.x += t.x; carry.y += t.y; carry.z += t.z; carry.w += t.w;
    }
    const int nc = c & 15;   // chunks before c within its group
    const float* csb = chunkS + ((size_t)bh * CC + (c & ~15)) * DD + g * 4;
    for (int cp = seg; cp < nc; cp += 4) {
        const float4 t = *(const float4*)(csb + (size_t)cp * DD);
        carry.x += t.x; carry.y += t.y; carry.z += t.z; carry.w += t.w;
    }
    xorred4(carry);

    // ---- phase 3b: time cumsum per d (seg-inclusive Hillis-Steele o=16,32)
    float4 i0 = kf0, i1 = kf1;
    {
        float u;
        u = __shfl_up(i0.x, 16, 64); if (seg >= 1) i0.x += u;
        u = __shfl_up(i0.y, 16, 64); if (seg >= 1) i0.y += u;
        u = __shfl_up(i0.z, 16, 64); if (seg >= 1) i0.z += u;
        u = __shfl_up(i0.w, 16, 64); if (seg >= 1) i0.w += u;
        u = __shfl_up(i1.x, 16, 64); if (seg >= 1) i1.x += u;
        u = __shfl_up(i1.y, 16, 64); if (seg >= 1) i1.y += u;
        u = __shfl_up(i1.z, 16, 64); if (seg >= 1) i1.z += u;
        u = __shfl_up(i1.w, 16, 64); if (seg >= 1) i1.w += u;
        u = __shfl_up(i0.x, 32, 64); if (seg >= 2) i0.x += u;
        u = __shfl_up(i0.y, 32, 64); if (seg >= 2) i0.y += u;
        u = __shfl_up(i0.z, 32, 64); if (seg >= 2) i0.z += u;
        u = __shfl_up(i0.w, 32, 64); if (seg >= 2) i0.w += u;
        u = __shfl_up(i1.x, 32, 64); if (seg >= 2) i1.x += u;
        u = __shfl_up(i1.y, 32, 64); if (seg >= 2) i1.y += u;
        u = __shfl_up(i1.z, 32, 64); if (seg >= 2) i1.z += u;
        u = __shfl_up(i1.w, 32, 64); if (seg >= 2) i1.w += u;
    }
    // S0[d] = chunk-first-half total = i0 at seg=3 (lane 48+g), broadcast
    float4 S0;
    S0.x = __shfl(i0.x, 48 + g, 64);
    S0.y = __shfl(i0.y, 48 + g, 64);
    S0.z = __shfl(i0.z, 48 + g, 64);
    S0.w = __shfl(i0.w, 48 + g, 64);

    float4 run0, run1;   // inclusive time-cumsum of feat(k) per d
    run0.x = carry.x + i0.x; run0.y = carry.y + i0.y;
    run0.z = carry.z + i0.z; run0.w = carry.w + i0.w;
    run1.x = carry.x + S0.x + i1.x; run1.y = carry.y + S0.y + i1.y;
    run1.z = carry.z + S0.z + i1.z; run1.w = carry.w + S0.w + i1.w;

    // ---- d-prefix (inclusive over d) per timestep: in-lane prefix + g-scan
    float4 p0, p1;
    p0.x = kf0.x; p0.y = p0.x + kf0.y; p0.z = p0.y + kf0.z; p0.w = p0.z + kf0.w;
    p1.x = kf1.x; p1.y = p1.x + kf1.y; p1.z = p1.y + kf1.z; p1.w = p1.z + kf1.w;
    float c0 = p0.w, c1 = p1.w;
    #pragma unroll
    for (int o = 1; o <= 8; o <<= 1) {
        float u0 = __shfl_up(c0, o, 16);
        float u1 = __shfl_up(c1, o, 16);
        if (g >= o) { c0 += u0; c1 += u1; }
    }
    const float e0 = c0 - p0.w;   // exclusive d-prefix entering this lane
    const float e1 = c1 - p1.w;

    // ---- reductions over d: s1 = qf.(d-prefix), s2 = qf.run (per timestep)
    const float sq0 = qf0.x + qf0.y + qf0.z + qf0.w;
    const float sq1 = qf1.x + qf1.y + qf1.z + qf1.w;
    float s1_0 = qf0.x * p0.x + qf0.y * p0.y + qf0.z * p0.z + qf0.w * p0.w + e0 * sq0;
    float s2_0 = qf0.x * run0.x + qf0.y * run0.y + qf0.z * run0.z + qf0.w * run0.w;
    float s1_1 = qf1.x * p1.x + qf1.y * p1.y + qf1.z * p1.z + qf1.w * p1.w + e1 * sq1;
    float s2_1 = qf1.x * run1.x + qf1.y * run1.y + qf1.z * run1.z + qf1.w * run1.w;
    #pragma unroll
    for (int o = 1; o <= 8; o <<= 1) {
        s1_0 += __shfl_xor(s1_0, o, 64);
        s2_0 += __shfl_xor(s2_0, o, 64);
        s1_1 += __shfl_xor(s1_1, o, 64);
        s2_1 += __shfl_xor(s2_1, o, 64);
    }

    const float r0 = s1_0 * __builtin_amdgcn_rcpf(s2_0);
    const float r1 = s1_1 * __builtin_amdgcn_rcpf(s2_1);
    float4 o0, o1;
    o0.x = vv0.x * r0; o0.y = vv0.y * r0; o0.z = vv0.z * r0; o0.w = vv0.w * r0;
    o1.x = vv1.x * r1; o1.y = vv1.y * r1; o1.z = vv1.z * r1; o1.w = vv1.w * r1;

    // ---- phase 4: all scratch reads done grid-wide, then overwrite out
    cg::this_grid().sync();

    *(float4*)(out + off0) = o0;
    *(float4*)(out + off1) = o1;
}

extern "C" void kernel_launch(void* const* d_in, const int* in_sizes, int n_in,
                              void* d_out, int out_size, void* d_ws, size_t ws_size,
                              hipStream_t stream) {
    const float* q = (const float*)d_in[0];
    const float* k = (const float*)d_in[1];
    const float* v = (const float*)d_in[2];
    float* out = (float*)d_out;
    (void)d_ws; (void)ws_size;            // workspace intentionally unused

    void* args[] = {(void*)&q, (void*)&k, (void*)&v, (void*)&out};
    hipLaunchCooperativeKernel((const void*)fused_kernel,
                               dim3(NWAVE / 4), dim3(256), args, 0, stream);
}

// Round 4
// 90.410 us; speedup vs baseline: 4.0397x; 4.0397x over previous
//
#include <hip/hip_runtime.h>

// Problem constants (B,T,H,D,M) = (2, 2048, 8, 64, 64), fp32 in/out.
#define BB 2
#define TT 2048
#define HH 8
#define DD 64
#define CC 256           // chunks over T
#define TC (TT / CC)     // 8 timesteps per chunk (= 4 segs x 2 iters)
#define STRIDE (HH * DD) // 512 floats between consecutive timesteps
#define NBH (BB * HH)    // 16
#define NG 16            // 16-chunk groups per (b,h)
#define GSZ 16           // chunks per group
#define GS_OFF ((size_t)NBH * CC * DD)  // float offset of group sums in ws

__device__ __forceinline__ float feat(float x) {
    // elu(x) + 1 = x+1 (x>0) else exp(x)
    return x > 0.f ? x + 1.f : __expf(x);
}

// Sum the 4 seg groups' values into every lane (butterfly over lanes ^16, ^32).
__device__ __forceinline__ void xorred4(float4& a) {
    a.x += __shfl_xor(a.x, 16, 64); a.y += __shfl_xor(a.y, 16, 64);
    a.z += __shfl_xor(a.z, 16, 64); a.w += __shfl_xor(a.w, 16, 64);
    a.x += __shfl_xor(a.x, 32, 64); a.y += __shfl_xor(a.y, 32, 64);
    a.z += __shfl_xor(a.z, 32, 64); a.w += __shfl_xor(a.w, 32, 64);
}

// Lane map: g = lane&15 -> d-group (d = 4g..4g+3), seg = lane>>4 -> timestep
// within group-of-4. One wave float4-load = 4 timesteps x 64 d = 1 KB.

// Kernel 1: one wave per (b,h,group-of-16-chunks). Emits the 16 chunk sums of
// feat(k) AND the group total. 256 blocks = 1 wave/CU; no atomics, no prefix
// kernel, no serialization.
__global__ void __launch_bounds__(64)
group_sums_kernel(const float* __restrict__ k, float* __restrict__ ws) {
    const int W    = blockIdx.x;              // bh*NG + g16
    const int g16  = W & (NG - 1);
    const int bh   = W >> 4;
    const int lane = threadIdx.x;
    const int g    = lane & 15;
    const int seg  = lane >> 4;

    float* chunkS = ws;            // [NBH][CC][DD] chunk sums
    float* groupS = ws + GS_OFF;   // [NBH][NG][DD] group sums

    const size_t base = (size_t)(bh >> 3) * TT * STRIDE
                      + (size_t)(bh & 7) * DD + g * 4;

    float4 gtot = make_float4(0.f, 0.f, 0.f, 0.f);
    #pragma unroll
    for (int i = 0; i < GSZ; ++i) {
        const int c = g16 * GSZ + i;
        const size_t o0 = base + (size_t)(c * TC + seg) * STRIDE;
        const float4 a = *(const float4*)(k + o0);
        const float4 b = *(const float4*)(k + o0 + (size_t)4 * STRIDE);
        float4 s;
        s.x = feat(a.x) + feat(b.x);
        s.y = feat(a.y) + feat(b.y);
        s.z = feat(a.z) + feat(b.z);
        s.w = feat(a.w) + feat(b.w);
        xorred4(s);                // all lanes now hold the chunk sum for their quad
        if (seg == 0)
            *(float4*)(chunkS + ((size_t)bh * CC + c) * DD + g * 4) = s;
        gtot.x += s.x; gtot.y += s.y; gtot.z += s.z; gtot.w += s.w;
    }
    if (seg == 0)
        *(float4*)(groupS + ((size_t)bh * NG + g16) * DD + g * 4) = gtot;
}

// Kernel 2: main. One wave per (b,h,c) chunk; exclusive carry assembled
// hierarchically (<=4 group + <=4 chunk float4 loads per lane, L2-resident).
__global__ void __launch_bounds__(64)
linattn_kernel(const float* __restrict__ q, const float* __restrict__ k,
               const float* __restrict__ v, const float* __restrict__ ws,
               float* __restrict__ out) {
    const int idx  = blockIdx.x;
    const int c    = idx & (CC - 1);
    const int h    = (idx >> 8) & (HH - 1);
    const int b    = idx >> 11;
    const int bh   = idx >> 8;
    const int lane = threadIdx.x;
    const int g    = lane & 15;
    const int seg  = lane >> 4;

    // lane's timesteps: t0 = c*TC + seg (iter 0), t0+4 (iter 1); d = 4g..4g+3
    const size_t off0 = (((size_t)b * TT + c * TC + seg) * HH + h) * DD + g * 4;
    const size_t off1 = off0 + (size_t)4 * STRIDE;

    // Issue all HBM loads first (independent; overlap with the carry gather).
    float4 kf0 = *(const float4*)(k + off0);
    float4 kf1 = *(const float4*)(k + off1);
    float4 qf0 = *(const float4*)(q + off0);
    float4 qf1 = *(const float4*)(q + off1);
    const float4 vv0 = *(const float4*)(v + off0);
    const float4 vv1 = *(const float4*)(v + off1);

    // ---- exclusive chunk carry: full groups before c's group + chunks before
    // c within its group. Seg-strided so each lane does <=4+4 loads.
    const float* chunkS = ws;
    const float* groupS = ws + GS_OFF;
    float4 carry = make_float4(0.f, 0.f, 0.f, 0.f);
    const int ng = c >> 4;          // full groups before this chunk's group
    const float* gsb = groupS + ((size_t)bh * NG) * DD + g * 4;
    for (int gp = seg; gp < ng; gp += 4) {
        const float4 t = *(const float4*)(gsb + (size_t)gp * DD);
        carry.x += t.x; carry.y += t.y; carry.z += t.z; carry.w += t.w;
    }
    const int nc = c & 15;          // chunks before c within its group
    const float* csb = chunkS + ((size_t)bh * CC + (c & ~15)) * DD + g * 4;
    for (int cp = seg; cp < nc; cp += 4) {
        const float4 t = *(const float4*)(csb + (size_t)cp * DD);
        carry.x += t.x; carry.y += t.y; carry.z += t.z; carry.w += t.w;
    }
    xorred4(carry);

    kf0.x = feat(kf0.x); kf0.y = feat(kf0.y); kf0.z = feat(kf0.z); kf0.w = feat(kf0.w);
    kf1.x = feat(kf1.x); kf1.y = feat(kf1.y); kf1.z = feat(kf1.z); kf1.w = feat(kf1.w);
    qf0.x = feat(qf0.x); qf0.y = feat(qf0.y); qf0.z = feat(qf0.z); qf0.w = feat(qf0.w);
    qf1.x = feat(qf1.x); qf1.y = feat(qf1.y); qf1.z = feat(qf1.z); qf1.w = feat(qf1.w);

    // ---- time cumsum per d: seg-inclusive scans of kf0/kf1 (Hillis-Steele o=16,32)
    float4 i0 = kf0, i1 = kf1;
    {
        float u;
        u = __shfl_up(i0.x, 16, 64); if (seg >= 1) i0.x += u;
        u = __shfl_up(i0.y, 16, 64); if (seg >= 1) i0.y += u;
        u = __shfl_up(i0.z, 16, 64); if (seg >= 1) i0.z += u;
        u = __shfl_up(i0.w, 16, 64); if (seg >= 1) i0.w += u;
        u = __shfl_up(i1.x, 16, 64); if (seg >= 1) i1.x += u;
        u = __shfl_up(i1.y, 16, 64); if (seg >= 1) i1.y += u;
        u = __shfl_up(i1.z, 16, 64); if (seg >= 1) i1.z += u;
        u = __shfl_up(i1.w, 16, 64); if (seg >= 1) i1.w += u;
        u = __shfl_up(i0.x, 32, 64); if (seg >= 2) i0.x += u;
        u = __shfl_up(i0.y, 32, 64); if (seg >= 2) i0.y += u;
        u = __shfl_up(i0.z, 32, 64); if (seg >= 2) i0.z += u;
        u = __shfl_up(i0.w, 32, 64); if (seg >= 2) i0.w += u;
        u = __shfl_up(i1.x, 32, 64); if (seg >= 2) i1.x += u;
        u = __shfl_up(i1.y, 32, 64); if (seg >= 2) i1.y += u;
        u = __shfl_up(i1.z, 32, 64); if (seg >= 2) i1.z += u;
        u = __shfl_up(i1.w, 32, 64); if (seg >= 2) i1.w += u;
    }
    // S0[d] = chunk-first-half total = i0 at seg=3 (lane 48+g), broadcast
    float4 S0;
    S0.x = __shfl(i0.x, 48 + g, 64);
    S0.y = __shfl(i0.y, 48 + g, 64);
    S0.z = __shfl(i0.z, 48 + g, 64);
    S0.w = __shfl(i0.w, 48 + g, 64);

    float4 run0, run1;   // inclusive time-cumsum of feat(k) per d
    run0.x = carry.x + i0.x; run0.y = carry.y + i0.y;
    run0.z = carry.z + i0.z; run0.w = carry.w + i0.w;
    run1.x = carry.x + S0.x + i1.x; run1.y = carry.y + S0.y + i1.y;
    run1.z = carry.z + S0.z + i1.z; run1.w = carry.w + S0.w + i1.w;

    // ---- d-prefix (inclusive over d) per timestep: in-lane prefix + group scan
    float4 p0, p1;
    p0.x = kf0.x; p0.y = p0.x + kf0.y; p0.z = p0.y + kf0.z; p0.w = p0.z + kf0.w;
    p1.x = kf1.x; p1.y = p1.x + kf1.y; p1.z = p1.y + kf1.z; p1.w = p1.z + kf1.w;
    float c0 = p0.w, c1 = p1.w;
    #pragma unroll
    for (int o = 1; o <= 8; o <<= 1) {
        float u0 = __shfl_up(c0, o, 16);
        float u1 = __shfl_up(c1, o, 16);
        if (g >= o) { c0 += u0; c1 += u1; }
    }
    const float e0 = c0 - p0.w;   // exclusive d-prefix entering this lane
    const float e1 = c1 - p1.w;

    // ---- reductions over d: s1 = qf.(d-prefix), s2 = qf.run (per timestep)
    const float sq0 = qf0.x + qf0.y + qf0.z + qf0.w;
    const float sq1 = qf1.x + qf1.y + qf1.z + qf1.w;
    float s1_0 = qf0.x * p0.x + qf0.y * p0.y + qf0.z * p0.z + qf0.w * p0.w + e0 * sq0;
    float s2_0 = qf0.x * run0.x + qf0.y * run0.y + qf0.z * run0.z + qf0.w * run0.w;
    float s1_1 = qf1.x * p1.x + qf1.y * p1.y + qf1.z * p1.z + qf1.w * p1.w + e1 * sq1;
    float s2_1 = qf1.x * run1.x + qf1.y * run1.y + qf1.z * run1.z + qf1.w * run1.w;
    #pragma unroll
    for (int o = 1; o <= 8; o <<= 1) {
        s1_0 += __shfl_xor(s1_0, o, 64);
        s2_0 += __shfl_xor(s2_0, o, 64);
        s1_1 += __shfl_xor(s1_1, o, 64);
        s2_1 += __shfl_xor(s2_1, o, 64);
    }

    const float r0 = s1_0 * __builtin_amdgcn_rcpf(s2_0);
    const float r1 = s1_1 * __builtin_amdgcn_rcpf(s2_1);
    float4 o0, o1;
    o0.x = vv0.x * r0; o0.y = vv0.y * r0; o0.z = vv0.z * r0; o0.w = vv0.w * r0;
    o1.x = vv1.x * r1; o1.y = vv1.y * r1; o1.z = vv1.z * r1; o1.w = vv1.w * r1;
    *(float4*)(out + off0) = o0;
    *(float4*)(out + off1) = o1;
}

extern "C" void kernel_launch(void* const* d_in, const int* in_sizes, int n_in,
                              void* d_out, int out_size, void* d_ws, size_t ws_size,
                              hipStream_t stream) {
    const float* q = (const float*)d_in[0];
    const float* k = (const float*)d_in[1];
    const float* v = (const float*)d_in[2];
    float* out = (float*)d_out;
    float* ws  = (float*)d_ws;            // needs NBH*CC*DD + NBH*NG*DD floats ≈ 1.06 MB

    group_sums_kernel<<<NBH * NG, 64, 0, stream>>>(k, ws);          // 256 blocks
    linattn_kernel<<<BB * HH * CC, 64, 0, stream>>>(q, k, v, ws, out); // 4096 blocks
}

// Round 5
// 78.863 us; speedup vs baseline: 4.6311x; 1.1464x over previous
//
#include <hip/hip_runtime.h>

// Problem constants (B,T,H,D,M) = (2, 2048, 8, 64, 64), fp32 in/out.
#define BB 2
#define TT 2048
#define HH 8
#define DD 64
#define CC 512           // chunks over T (thin chunks)
#define TC (TT / CC)     // 4 timesteps per chunk = one per seg group
#define STRIDE (HH * DD) // 512 floats between consecutive timesteps
#define NBH (BB * HH)    // 16
#define PW (CC / 16)     // 32 chunks per wave in prefix_kernel

__device__ __forceinline__ float feat(float x) {
    // elu(x) + 1 = x+1 (x>0) else exp(x)
    return x > 0.f ? x + 1.f : __expf(x);
}

__device__ __forceinline__ void feat4(float4& a) {
    a.x = feat(a.x); a.y = feat(a.y); a.z = feat(a.z); a.w = feat(a.w);
}

// Sum the 4 seg groups' values into every lane (butterfly over lanes ^16, ^32).
__device__ __forceinline__ void xorred4(float4& a) {
    a.x += __shfl_xor(a.x, 16, 64); a.y += __shfl_xor(a.y, 16, 64);
    a.z += __shfl_xor(a.z, 16, 64); a.w += __shfl_xor(a.w, 16, 64);
    a.x += __shfl_xor(a.x, 32, 64); a.y += __shfl_xor(a.y, 32, 64);
    a.z += __shfl_xor(a.z, 32, 64); a.w += __shfl_xor(a.w, 32, 64);
}

// Lane map: g = lane&15 -> d-group (d = 4g..4g+3), seg = lane>>4 -> timestep.
// One wave float4-load = 4 timesteps x 64 d = 1 KB.

// Kernel 1: per (b,h) pair-of-chunks sums of feat(k). One wave per 8 timesteps
// (2 thin chunks) -- identical loads to the round-0 kernel, two outputs.
__global__ void __launch_bounds__(64)
chunk_sums_kernel(const float* __restrict__ k, float* __restrict__ ws) {
    const int idx  = blockIdx.x;              // bh*256 + p  (p = chunk pair)
    const int p    = idx & 255;
    const int h    = (idx >> 8) & (HH - 1);
    const int b    = idx >> 11;
    const int bh   = idx >> 8;
    const int lane = threadIdx.x;
    const int g    = lane & 15;
    const int seg  = lane >> 4;

    const size_t off0 = (((size_t)b * TT + p * 8 + seg) * HH + h) * DD + g * 4;
    float4 k0 = *(const float4*)(k + off0);
    float4 k1 = *(const float4*)(k + off0 + (size_t)4 * STRIDE);

    feat4(k0); feat4(k1);
    xorred4(k0);      // chunk 2p   sum (timesteps p*8 .. p*8+3)
    xorred4(k1);      // chunk 2p+1 sum (timesteps p*8+4 .. p*8+7)

    if (seg == 0) {
        *(float4*)(ws + ((size_t)bh * CC + 2 * p) * DD + g * 4)     = k0;
        *(float4*)(ws + ((size_t)bh * CC + 2 * p + 1) * DD + g * 4) = k1;
    }
}

// Kernel 2: in-place ws chunk sums -> EXCLUSIVE prefix over c (per bh, per d).
__global__ void __launch_bounds__(1024)
prefix_kernel(float* __restrict__ ws) {
    const int bh   = blockIdx.x;              // 0..15
    const int lane = threadIdx.x & 63;        // d
    const int w    = threadIdx.x >> 6;        // wave id 0..15

    size_t base = ((size_t)bh * CC + w * PW) * DD + lane;

    float val[PW];
    #pragma unroll
    for (int i = 0; i < PW; ++i) val[i] = ws[base + (size_t)i * DD];

    float run = 0.f, excl[PW];
    #pragma unroll
    for (int i = 0; i < PW; ++i) { excl[i] = run; run += val[i]; }

    __shared__ float tot[16][DD];
    tot[w][lane] = run;
    __syncthreads();

    float carry = 0.f;
    for (int w2 = 0; w2 < w; ++w2) carry += tot[w2][lane];

    #pragma unroll
    for (int i = 0; i < PW; ++i) ws[base + (size_t)i * DD] = excl[i] + carry;
}

// Kernel 3: main. One wave per thin (b,h,c) chunk = 4 timesteps.
// Half the dependent-chain depth of the round-0 kernel, 2x the waves.
__global__ void __launch_bounds__(64)
linattn_kernel(const float* __restrict__ q, const float* __restrict__ k,
               const float* __restrict__ v, const float* __restrict__ ws,
               float* __restrict__ out) {
    const int idx  = blockIdx.x;              // bh*CC + c
    const int c    = idx & (CC - 1);
    const int bh   = idx >> 9;
    const int h    = bh & (HH - 1);
    const int b    = bh >> 3;
    const int lane = threadIdx.x;
    const int g    = lane & 15;
    const int seg  = lane >> 4;

    // lane's timestep: t = c*4 + seg; d = 4g..4g+3
    const size_t off = (((size_t)b * TT + c * TC + seg) * HH + h) * DD + g * 4;

    float4 kf = *(const float4*)(k + off);
    float4 qf = *(const float4*)(q + off);
    const float4 vv = *(const float4*)(v + off);
    const float4 carry = *(const float4*)(ws + (size_t)idx * DD + g * 4);

    feat4(kf); feat4(qf);

    // ---- time cumsum per d: seg-inclusive scan (Hillis-Steele o=16,32)
    float4 i0 = kf;
    {
        float u;
        u = __shfl_up(i0.x, 16, 64); if (seg >= 1) i0.x += u;
        u = __shfl_up(i0.y, 16, 64); if (seg >= 1) i0.y += u;
        u = __shfl_up(i0.z, 16, 64); if (seg >= 1) i0.z += u;
        u = __shfl_up(i0.w, 16, 64); if (seg >= 1) i0.w += u;
        u = __shfl_up(i0.x, 32, 64); if (seg >= 2) i0.x += u;
        u = __shfl_up(i0.y, 32, 64); if (seg >= 2) i0.y += u;
        u = __shfl_up(i0.z, 32, 64); if (seg >= 2) i0.z += u;
        u = __shfl_up(i0.w, 32, 64); if (seg >= 2) i0.w += u;
    }
    float4 run;          // inclusive time-cumsum of feat(k) per d
    run.x = carry.x + i0.x; run.y = carry.y + i0.y;
    run.z = carry.z + i0.z; run.w = carry.w + i0.w;

    // ---- d-prefix (inclusive over d) at this timestep: in-lane + g-scan
    float4 p;
    p.x = kf.x; p.y = p.x + kf.y; p.z = p.y + kf.z; p.w = p.z + kf.w;
    float cg = p.w;
    #pragma unroll
    for (int o = 1; o <= 8; o <<= 1) {
        const float u = __shfl_up(cg, o, 16);
        if (g >= o) cg += u;
    }
    const float e = cg - p.w;    // exclusive d-prefix entering this lane

    // ---- reductions over d (within the 16-lane seg group)
    const float sq = qf.x + qf.y + qf.z + qf.w;
    float s1 = qf.x * p.x + qf.y * p.y + qf.z * p.z + qf.w * p.w + e * sq;
    float s2 = qf.x * run.x + qf.y * run.y + qf.z * run.z + qf.w * run.w;
    #pragma unroll
    for (int o = 1; o <= 8; o <<= 1) {
        s1 += __shfl_xor(s1, o, 64);
        s2 += __shfl_xor(s2, o, 64);
    }

    const float r = s1 * __builtin_amdgcn_rcpf(s2);
    float4 ov;
    ov.x = vv.x * r; ov.y = vv.y * r; ov.z = vv.z * r; ov.w = vv.w * r;
    *(float4*)(out + off) = ov;
}

extern "C" void kernel_launch(void* const* d_in, const int* in_sizes, int n_in,
                              void* d_out, int out_size, void* d_ws, size_t ws_size,
                              hipStream_t stream) {
    const float* q = (const float*)d_in[0];
    const float* k = (const float*)d_in[1];
    const float* v = (const float*)d_in[2];
    float* out = (float*)d_out;
    float* ws  = (float*)d_ws;            // needs NBH*CC*DD*4 = 2 MB

    chunk_sums_kernel<<<NBH * 256, 64, 0, stream>>>(k, ws);         // 4096 blocks
    prefix_kernel<<<NBH, 1024, 0, stream>>>(ws);                    // 16 blocks
    linattn_kernel<<<NBH * CC, 64, 0, stream>>>(q, k, v, ws, out);  // 8192 blocks
}